// Round 7
// baseline (14761.374 us; speedup 1.0000x reference)
//
#include <hip/hip_runtime.h>
#include <hip/hip_bf16.h>
#include <stdint.h>

// Problem constants
#define T_STEPS 128
#define BATCH   2048
#define IN_DIM  18
#define HID     256
#define G3      768

// Fragment repack (unchanged layout from R3)
#define NT   48
#define KT0  9
#define KT1  16
#define L0_FRAGS (NT * KT0)  // 432
#define L1_FRAGS (NT * KT1)  // 768
#define TOT_FRAGS (L0_FRAGS + L1_FRAGS)  // 1200 x 1KB

// Grid: 16 groups (128 rows) x 16 slices (16 cols). blockIdx = slice*16+group
// => a group's 16 blocks share blockIdx mod 8 => same XCD (L2-local exchange).
#define GROUPS 16
#define SLICES 16
#define NBLK   256
#define TPB    512           // 8 waves; wave w owns rows [w*16, w*16+16)

// d_ws layout
#define FLAGS_OFF  1310720u                    // flags: 256 half-steps x 16 x 16
#define N_FLAGS    (256 * GROUPS * SLICES)     // 65536 u32 = 256 KB
#define HX_OFF     1572864u                    // hx: [L][p][group][128][256] bf16 = 4MB

using frag_ab = __attribute__((ext_vector_type(8))) short;
using f32x4   = __attribute__((ext_vector_type(4))) float;

__device__ __forceinline__ unsigned short f2bf(float f) {
  unsigned int u = __float_as_uint(f);
  u = (u + 0x7fffu + ((u >> 16) & 1u)) >> 16;  // RNE
  return (unsigned short)u;
}
__device__ __forceinline__ float sigmoidf_(float v) {
  return 1.f / (1.f + __expf(-v));
}
__device__ __forceinline__ float tanhf_(float v) {
  float a = fabsf(v);
  float e = __expf(-2.f * a);
  float r = (1.f - e) / (1.f + e);
  return v < 0.f ? -r : r;
}
__device__ __forceinline__ f32x4 mfma16(frag_ab a, frag_ab b, f32x4 c) {
  return __builtin_amdgcn_mfma_f32_16x16x32_bf16(a, b, c, 0, 0, 0);
}
__device__ __forceinline__ uint32_t hxoff(int L, int p, int group) {
  return (uint32_t)(((L * 2 + p) * GROUPS + group) * 65536);  // 128*512B
}

// ---------------------------------------------------------------------------
// Prologue 1: fp32 weights -> bf16 MFMA B-fragments (single copy).
// Fragment f: lane L, elems j hold B[k=kt*32+(L>>4)*8+j][n=ntile*16+(L&15)].
// ---------------------------------------------------------------------------
__global__ __launch_bounds__(256) void repack_w(
    const float* __restrict__ Wih0, const float* __restrict__ Whh0,
    const float* __restrict__ Wih1, const float* __restrict__ Whh1,
    unsigned short* __restrict__ wq)
{
  int g = blockIdx.x * 256 + threadIdx.x;
  if (g >= TOT_FRAGS * 64) return;
  int f = g >> 6;
  int L = g & 63;
  int q = L >> 4, c16 = L & 15;
  unsigned short v[8];
  if (f < L0_FRAGS) {
    int n = f / KT0, kt = f - n * KT0;
    int col = n * 16 + c16;
    if (kt == 0) {
      #pragma unroll
      for (int j = 0; j < 8; ++j) {
        int k = q * 8 + j;
        v[j] = (k < IN_DIM) ? f2bf(Wih0[col * IN_DIM + k]) : (unsigned short)0;
      }
    } else {
      int kb = (kt - 1) * 32 + q * 8;
      #pragma unroll
      for (int j = 0; j < 8; ++j) v[j] = f2bf(Whh0[col * HID + kb + j]);
    }
  } else {
    int f1 = f - L0_FRAGS;
    int n = f1 / KT1, kt = f1 - n * KT1;
    int col = n * 16 + c16;
    const float* __restrict__ W = (kt < 8) ? Wih1 : Whh1;
    int kb = (kt & 7) * 32 + q * 8;
    #pragma unroll
    for (int j = 0; j < 8; ++j) v[j] = f2bf(W[col * HID + kb + j]);
  }
  frag_ab pv;
  #pragma unroll
  for (int j = 0; j < 8; ++j) pv[j] = (short)v[j];
  *(frag_ab*)((char*)wq + ((size_t)f << 10) + (size_t)(L << 4)) = pv;
}

// ---------------------------------------------------------------------------
// Prologue 2: zero flags + the parity-1 h slots (initial h = 0).
// ---------------------------------------------------------------------------
__global__ __launch_bounds__(256) void clear_ws(uint32_t* __restrict__ flags,
                                                uint32_t* __restrict__ hxu) {
  int i = blockIdx.x * 256 + threadIdx.x;
  if (i < N_FLAGS) flags[i] = 0;
  if (i < 262144) {
    hxu[262144 + i]     = 0;   // hx[L=0][p=1]  (h1(-1) = 0)
    hxu[3 * 262144 + i] = 0;   // hx[L=1][p=1]  (h2(-1) = 0)
  }
}

// ---------------------------------------------------------------------------
// Weight-stationary GRU: weights in LDS, h exchanged via L2-resident buffer,
// flags release/acquire per half-step (wait only on half-step i-1).
// ---------------------------------------------------------------------------
__global__ __launch_bounds__(TPB, 2) void gru_ws(
    const float* __restrict__ x,
    const float* __restrict__ bih0, const float* __restrict__ bhh0,
    const float* __restrict__ bih1, const float* __restrict__ bhh1,
    const float* __restrict__ fcw,  const float* __restrict__ fcb,
    const unsigned short* __restrict__ wq,
    uint32_t* __restrict__ flags,
    char* __restrict__ hx,
    float* __restrict__ out)
{
  // 75 KB weights + 8 KB x-strip = 85 KB -> 1 block/CU
  __shared__ __align__(16) unsigned short lw[38400];   // L0: 27 frags, L1: 48
  __shared__ __align__(16) unsigned short xs[128 * 32];

  const int tid   = threadIdx.x;
  const int w     = tid >> 6;          // wave 0..7 -> rows [w*16, w*16+16)
  const int lane  = tid & 63;
  const int q     = lane >> 4;
  const int m     = lane & 15;
  const int group = blockIdx.x & 15;
  const int slice = blockIdx.x >> 4;
  const int row0  = group * 128;       // batch row base
  const int wrow  = w * 16;

  // ---- copy this slice's 75 fragments into LDS ----
  for (int idx = tid; idx < 75 * 64; idx += TPB) {
    int j = idx >> 6, l = idx & 63;
    int f;
    if (j < 27) { int g = j / 9;  int kt = j - g * 9;  f = (g * 16 + slice) * KT0 + kt; }
    else { int j2 = j - 27; int g = j2 >> 4; int kt = j2 & 15;
           f = L0_FRAGS + (g * 16 + slice) * KT1 + kt; }
    *(frag_ab*)((char*)lw + (size_t)j * 1024 + (size_t)(l << 4)) =
        *(const frag_ab*)((const char*)wq + ((size_t)f << 10) + (size_t)(l << 4));
  }
  for (int idx = tid; idx < 128 * 32; idx += TPB) xs[idx] = 0;
  __syncthreads();
  // stage x(0)
  for (int idx = tid; idx < 128 * IN_DIM; idx += TPB) {
    int r = idx / IN_DIM, cc = idx - r * IN_DIM;
    xs[r * 32 + cc] = f2bf(x[(size_t)(row0 + r) * IN_DIM + cc]);
  }

  // ---- per-lane biases (col = slice*16 + m) ----
  const int c = slice * 16 + m;
  const float l0_brc = bih0[c]         + bhh0[c];
  const float l0_bzc = bih0[HID + c]   + bhh0[HID + c];
  const float l0_bni = bih0[2*HID + c];
  const float l0_bnh = bhh0[2*HID + c];
  const float l1_brc = bih1[c]         + bhh1[c];
  const float l1_bzc = bih1[HID + c]   + bhh1[HID + c];
  const float l1_bni = bih1[2*HID + c];
  const float l1_bnh = bhh1[2*HID + c];
  __syncthreads();

  float h1m[4] = {0, 0, 0, 0}, h2m[4] = {0, 0, 0, 0};
  int dead = 0;
  const char* lwb = (const char*)lw;
  const int lb = lane << 4;
  const int rb = (wrow + m) * 512 + q * 16;  // A-frag row/quad byte offset

#define WAIT_FLAGS(I)                                                        \
  do {                                                                       \
    if (tid < SLICES) {                                                      \
      uint32_t* fp = &flags[((I) * GROUPS + group) * SLICES + tid];          \
      int it = 0, bound = dead ? 64 : (1 << 22);                             \
      while (__hip_atomic_load(fp, __ATOMIC_ACQUIRE,                         \
                               __HIP_MEMORY_SCOPE_AGENT) == 0) {             \
        if (++it >= bound) { dead = 1; break; }                              \
        __builtin_amdgcn_s_sleep(1);                                         \
      }                                                                      \
    }                                                                        \
    __syncthreads();                                                         \
  } while (0)

#define PUBLISH(I)                                                           \
  do {                                                                       \
    __threadfence();                                                         \
    __syncthreads();                                                         \
    if (tid == 0)                                                            \
      __hip_atomic_store(&flags[((I) * GROUPS + group) * SLICES + slice],    \
                         1u, __ATOMIC_RELEASE, __HIP_MEMORY_SCOPE_AGENT);    \
  } while (0)

  for (int t = 0; t < T_STEPS; ++t) {
    const int p = t & 1, pm1 = p ^ 1;

    // ================= L0 (half-step 2t): A = [x(t) | h1(t-1)] =============
    if (t > 0) { WAIT_FLAGS(2 * t - 1); }
    {
      const frag_ab a0 = *(const frag_ab*)&xs[(wrow + m) * 32 + q * 8];
      frag_ab ah[8];
      const char* hb = hx + hxoff(0, pm1, group);
      #pragma unroll
      for (int kt = 0; kt < 8; ++kt)
        ah[kt] = *(const frag_ab*)(hb + rb + kt * 64);

      f32x4 ar = {0,0,0,0}, az = {0,0,0,0}, anx = {0,0,0,0}, anh = {0,0,0,0};
      {  // kt = 0 (x part)
        frag_ab br = *(const frag_ab*)(lwb + (0 * 9 + 0) * 1024 + lb);
        frag_ab bz = *(const frag_ab*)(lwb + (1 * 9 + 0) * 1024 + lb);
        frag_ab bn = *(const frag_ab*)(lwb + (2 * 9 + 0) * 1024 + lb);
        ar  = mfma16(a0, br, ar);
        az  = mfma16(a0, bz, az);
        anx = mfma16(a0, bn, anx);
      }
      #pragma unroll
      for (int kt = 1; kt < 9; ++kt) {
        frag_ab br = *(const frag_ab*)(lwb + (0 * 9 + kt) * 1024 + lb);
        frag_ab bz = *(const frag_ab*)(lwb + (1 * 9 + kt) * 1024 + lb);
        frag_ab bn = *(const frag_ab*)(lwb + (2 * 9 + kt) * 1024 + lb);
        ar  = mfma16(ah[kt - 1], br, ar);
        az  = mfma16(ah[kt - 1], bz, az);
        anh = mfma16(ah[kt - 1], bn, anh);
      }
      char* wb = hx + hxoff(0, p, group);
      #pragma unroll
      for (int rr = 0; rr < 4; ++rr) {
        float rg = sigmoidf_(ar[rr] + l0_brc);
        float zg = sigmoidf_(az[rr] + l0_bzc);
        float ng = tanhf_(anx[rr] + l0_bni + rg * (anh[rr] + l0_bnh));
        float hnew = (1.f - zg) * ng + zg * h1m[rr];
        h1m[rr] = hnew;
        *(unsigned short*)(wb + (wrow + q * 4 + rr) * 512 + c * 2) = f2bf(hnew);
      }
    }
    PUBLISH(2 * t);

    // ================= L1 (half-step 2t+1): A = [h1(t) | h2(t-1)] ==========
    WAIT_FLAGS(2 * t);
    // stage x(t+1) (xs not read during L1; next read after WAIT(2t+1))
    if (t + 1 < T_STEPS) {
      for (int idx = tid; idx < 128 * IN_DIM; idx += TPB) {
        int r = idx / IN_DIM, cc = idx - r * IN_DIM;
        xs[r * 32 + cc] =
            f2bf(x[(size_t)((t + 1) * BATCH + row0 + r) * IN_DIM + cc]);
      }
    }
    {
      frag_ab b1[16];
      const char* h1b = hx + hxoff(0, p, group);
      const char* h2b = hx + hxoff(1, pm1, group);
      #pragma unroll
      for (int kt = 0; kt < 8; ++kt)
        b1[kt] = *(const frag_ab*)(h1b + rb + kt * 64);
      #pragma unroll
      for (int kt = 0; kt < 8; ++kt)
        b1[8 + kt] = *(const frag_ab*)(h2b + rb + kt * 64);

      f32x4 ar = {0,0,0,0}, az = {0,0,0,0}, anx = {0,0,0,0}, anh = {0,0,0,0};
      #pragma unroll
      for (int kt = 0; kt < 16; ++kt) {
        frag_ab br = *(const frag_ab*)(lwb + 27648 + (0 * 16 + kt) * 1024 + lb);
        frag_ab bz = *(const frag_ab*)(lwb + 27648 + (1 * 16 + kt) * 1024 + lb);
        frag_ab bn = *(const frag_ab*)(lwb + 27648 + (2 * 16 + kt) * 1024 + lb);
        ar = mfma16(b1[kt], br, ar);
        az = mfma16(b1[kt], bz, az);
        if (kt < 8) anx = mfma16(b1[kt], bn, anx);   // W_ih1 @ h1(t)
        else        anh = mfma16(b1[kt], bn, anh);   // W_hh1 @ h2(t-1)
      }
      char* wb = hx + hxoff(1, p, group);
      #pragma unroll
      for (int rr = 0; rr < 4; ++rr) {
        float rg = sigmoidf_(ar[rr] + l1_brc);
        float zg = sigmoidf_(az[rr] + l1_bzc);
        float ng = tanhf_(anx[rr] + l1_bni + rg * (anh[rr] + l1_bnh));
        float hnew = (1.f - zg) * ng + zg * h2m[rr];
        h2m[rr] = hnew;
        *(unsigned short*)(wb + (wrow + q * 4 + rr) * 512 + c * 2) = f2bf(hnew);
      }
    }
    PUBLISH(2 * t + 1);
  }

  // ---- FC head: slice-0 blocks, after everyone's final publish ----
  if (slice == 0) {
    WAIT_FLAGS(255);
    const int row = tid >> 2, o = tid & 3;       // 512 threads = 128 rows x 4
    const char* h2b = hx + hxoff(1, 1, group);   // h2(127), parity 1
    const float* wrow2 = &fcw[o * HID];
    float acc = fcb[o];
    #pragma unroll 8
    for (int k = 0; k < HID; ++k) {
      uint32_t u = (uint32_t)(*(const unsigned short*)(h2b + row * 512 + k * 2)) << 16;
      acc += __uint_as_float(u) * wrow2[k];
    }
    float sg = 1.f / (1.f + __expf(-acc));
    out[(size_t)(row0 + row) * 4 + o] = sg * 2.f - 1.f;
  }
#undef WAIT_FLAGS
#undef PUBLISH
}

extern "C" void kernel_launch(void* const* d_in, const int* in_sizes, int n_in,
                              void* d_out, int out_size, void* d_ws, size_t ws_size,
                              hipStream_t stream) {
  const float* x    = (const float*)d_in[0];
  const float* Wih0 = (const float*)d_in[1];
  const float* Whh0 = (const float*)d_in[2];
  const float* bih0 = (const float*)d_in[3];
  const float* bhh0 = (const float*)d_in[4];
  const float* Wih1 = (const float*)d_in[5];
  const float* Whh1 = (const float*)d_in[6];
  const float* bih1 = (const float*)d_in[7];
  const float* bhh1 = (const float*)d_in[8];
  const float* fcw  = (const float*)d_in[9];
  const float* fcb  = (const float*)d_in[10];

  unsigned short* wq = (unsigned short*)d_ws;
  uint32_t* flags = (uint32_t*)((char*)d_ws + FLAGS_OFF);
  char*     hx    = (char*)d_ws + HX_OFF;

  repack_w<<<(TOT_FRAGS * 64 + 255) / 256, 256, 0, stream>>>(Wih0, Whh0, Wih1, Whh1, wq);
  clear_ws<<<(262144 + 255) / 256, 256, 0, stream>>>(flags, (uint32_t*)hx);
  gru_ws<<<NBLK, TPB, 0, stream>>>(x, bih0, bhh0, bih1, bhh1, fcw, fcb, wq,
                                   flags, hx, (float*)d_out);
}

// Round 8
// 1027.946 us; speedup vs baseline: 14.3601x; 14.3601x over previous
//
#include <hip/hip_runtime.h>
#include <hip/hip_bf16.h>
#include <stdint.h>

// Problem constants
#define T_STEPS 128
#define BATCH   2048
#define IN_DIM  18
#define HID     256

// Fragment repack (same layout as R3)
#define NT   48
#define KT0  9
#define KT1  16
#define L0_FRAGS 432
#define L1_FRAGS 768
#define TOT_FRAGS 1200

// d_ws layout (total need ~17.7 MB)
#define CNT_OFF  1310720u
#define CNTA(g)  (CNT_OFF + (uint32_t)(g) * 64u)
#define CNTB(g)  (CNT_OFF + 4096u + (uint32_t)(g) * 64u)
#define CNTC(g)  (CNT_OFF + 8192u + (uint32_t)(g) * 64u)
#define H1_OFF   1441792u
#define H1SLOT(t, g) (H1_OFF + (uint32_t)(((((t) & 3) * 64) + (g)) * 16384))
#define XG_OFF   5898240u
#define XGSLOT(t, g) (XG_OFF + (uint32_t)(((((t) & 3) * 64) + (g)) * 49152))

using frag_ab = __attribute__((ext_vector_type(8))) short;
using f32x4   = __attribute__((ext_vector_type(4))) float;
using uint4v  = __attribute__((ext_vector_type(4))) unsigned int;
using uint2v  = __attribute__((ext_vector_type(2))) unsigned int;

__device__ __forceinline__ unsigned short f2bf(float f) {
  unsigned int u = __float_as_uint(f);
  u = (u + 0x7fffu + ((u >> 16) & 1u)) >> 16;  // RNE
  return (unsigned short)u;
}
__device__ __forceinline__ float bf2f(unsigned short v) {
  return __uint_as_float((uint32_t)v << 16);
}
__device__ __forceinline__ float sigmoidf_(float v) {
  return 1.f / (1.f + __expf(-v));
}
__device__ __forceinline__ float tanhf_(float v) {
  float a = fabsf(v);
  float e = __expf(-2.f * a);
  float r = (1.f - e) / (1.f + e);
  return v < 0.f ? -r : r;
}
__device__ __forceinline__ f32x4 mfma16(frag_ab a, frag_ab b, f32x4 c) {
  return __builtin_amdgcn_mfma_f32_16x16x32_bf16(a, b, c, 0, 0, 0);
}

// ---------------------------------------------------------------------------
// Prologue 1: fp32 weights -> bf16 MFMA B-fragments (layout as R3).
// ---------------------------------------------------------------------------
__global__ __launch_bounds__(256) void repack_w(
    const float* __restrict__ Wih0, const float* __restrict__ Whh0,
    const float* __restrict__ Wih1, const float* __restrict__ Whh1,
    unsigned short* __restrict__ wq)
{
  int g = blockIdx.x * 256 + threadIdx.x;
  if (g >= TOT_FRAGS * 64) return;
  int f = g >> 6;
  int L = g & 63;
  int q = L >> 4, c16 = L & 15;
  unsigned short v[8];
  if (f < L0_FRAGS) {
    int n = f / KT0, kt = f - n * KT0;
    int col = n * 16 + c16;
    if (kt == 0) {
      #pragma unroll
      for (int j = 0; j < 8; ++j) {
        int k = q * 8 + j;
        v[j] = (k < IN_DIM) ? f2bf(Wih0[col * IN_DIM + k]) : (unsigned short)0;
      }
    } else {
      int kb = (kt - 1) * 32 + q * 8;
      #pragma unroll
      for (int j = 0; j < 8; ++j) v[j] = f2bf(Whh0[col * HID + kb + j]);
    }
  } else {
    int f1 = f - L0_FRAGS;
    int n = f1 / KT1, kt = f1 - n * KT1;
    int col = n * 16 + c16;
    const float* __restrict__ W = (kt < 8) ? Wih1 : Whh1;
    int kb = (kt & 7) * 32 + q * 8;
    #pragma unroll
    for (int j = 0; j < 8; ++j) v[j] = f2bf(W[col * HID + kb + j]);
  }
  frag_ab pv;
  #pragma unroll
  for (int j = 0; j < 8; ++j) pv[j] = (short)v[j];
  *(frag_ab*)((char*)wq + ((size_t)f << 10) + (size_t)(L << 4)) = pv;
}

// ---------------------------------------------------------------------------
// Prologue 2: zero the counters (d_ws poisoned each launch).
// ---------------------------------------------------------------------------
__global__ __launch_bounds__(256) void clear_cnt(uint32_t* __restrict__ c) {
  int i = blockIdx.x * 256 + threadIdx.x;
  if (i < 3072) c[i] = 0;
}

// ---------------------------------------------------------------------------
// 3-stage pipeline: A (layer0) -> B (h1 @ W_ih1^T) -> C (h2 recurrence + FC).
// 64 blocks per stage, M=32 rows. All cross-block data/flags via sc0 sc1
// (coherence-point) accesses -- no fences, no L2 invalidation, weight stream
// stays L2-cached. Ring depth 4 absorbs the natural 2-step stage lag.
// ---------------------------------------------------------------------------
__global__ __launch_bounds__(1024) void gru_pipe(
    const float* __restrict__ x,
    const float* __restrict__ bih0, const float* __restrict__ bhh0,
    const float* __restrict__ bih1, const float* __restrict__ bhh1,
    const float* __restrict__ fcw,  const float* __restrict__ fcb,
    char* __restrict__ ws,
    float* __restrict__ out)
{
  __shared__ __align__(16) char smem[82944];   // 81 KB -> 1 block/CU

  const int tid  = threadIdx.x;
  const int wave = tid >> 6;
  const int lane = tid & 63;
  const int q    = lane >> 4;
  const int c16  = lane & 15;
  const int bid  = blockIdx.x;
  const uint32_t lane16 = (uint32_t)(lane << 4);
  int dead = 0;

#define BARRIER() asm volatile("s_waitcnt lgkmcnt(0)\n\ts_barrier" ::: "memory")
#define ISSUE3(sl, oR, oZ, oN)                                              \
  asm volatile("global_load_dwordx4 %0, %3, %6\n\t"                         \
               "global_load_dwordx4 %1, %4, %6\n\t"                         \
               "global_load_dwordx4 %2, %5, %6"                             \
               : "=&v"(rr_[sl]), "=&v"(rz_[sl]), "=&v"(rn_[sl])             \
               : "v"((uint32_t)(oR)), "v"((uint32_t)(oZ)),                  \
                 "v"((uint32_t)(oN)), "s"(ws)                               \
               : "memory")
#define WAIT3(sl, NSTR)                                                     \
  asm volatile("s_waitcnt vmcnt(" NSTR ")"                                  \
               : "+v"(rr_[sl]), "+v"(rz_[sl]), "+v"(rn_[sl]) :: "memory")
#define SCLOAD4(dst, off)                                                   \
  asm volatile("global_load_dwordx4 %0, %1, %2 sc0 sc1"                     \
               : "=&v"(dst) : "v"((uint32_t)(off)), "s"(ws) : "memory")
#define SCSTORE4(off, val)                                                  \
  asm volatile("global_store_dwordx4 %0, %1, %2 sc0 sc1"                    \
               :: "v"((uint32_t)(off)), "v"(val), "s"(ws) : "memory")
#define SCSTORE2(off, val)                                                  \
  asm volatile("global_store_dwordx2 %0, %1, %2 sc0 sc1"                    \
               :: "v"((uint32_t)(off)), "v"(val), "s"(ws) : "memory")
#define PUBLISH(off, val)                                                   \
  asm volatile("global_store_dword %0, %1, %2 sc0 sc1"                      \
               :: "v"((uint32_t)(off)), "v"((uint32_t)(val)), "s"(ws)       \
               : "memory")
#define POLL(off, target)                                                   \
  do {                                                                      \
    int tgt = (target);                                                     \
    if (tgt > 0) {                                                          \
      int it = 0, bound = dead ? 64 : (1 << 17);                            \
      for (;;) {                                                            \
        uint32_t v_;                                                        \
        asm volatile("global_load_dword %0, %1, %2 sc0 sc1\n\t"             \
                     "s_waitcnt vmcnt(0)"                                   \
                     : "=&v"(v_) : "v"((uint32_t)(off)), "s"(ws)            \
                     : "memory");                                           \
        if ((int)v_ >= tgt) break;                                          \
        if (++it >= bound) { dead = 1; break; }                             \
        __builtin_amdgcn_s_sleep(2);                                        \
      }                                                                     \
    }                                                                       \
  } while (0)

  // =========================================================================
  if (bid < 64) {
    // ----------------------------- Stage A: layer 0 -----------------------
    const int g = bid, row0 = g * 32;
    unsigned short (*h1b)[264] = (unsigned short (*)[264])smem;       // [2*32][264]
    unsigned short (*xs)[32]   = (unsigned short (*)[32])(smem + 33792); // [2*32][32]
    for (int i = tid; i < 2 * 32 * 264; i += 1024) ((unsigned short*)smem)[i] = 0;
    for (int i = tid; i < 2 * 32 * 32; i += 1024) ((unsigned short*)(smem + 33792))[i] = 0;
    const int c = wave * 16 + c16;
    const float brc = bih0[c] + bhh0[c];
    const float bzc = bih0[HID + c] + bhh0[HID + c];
    const float bni = bih0[2 * HID + c];
    const float bnh = bhh0[2 * HID + c];
    {  // x(0)
      int r = tid & 31, cc = tid >> 5;
      float xv = x[(size_t)(row0 + r) * IN_DIM + (cc < 18 ? cc : 17)];
      if (cc < 18) xs[r][cc] = f2bf(xv);
    }
    __syncthreads();

    const uint32_t b0r = (uint32_t)((wave * KT0) << 10);
    const uint32_t b0z = (uint32_t)(((16 + wave) * KT0) << 10);
    const uint32_t b0n = (uint32_t)(((32 + wave) * KT0) << 10);
    frag_ab rr_[3], rz_[3], rn_[3];
    float h1m[2][4] = {{0, 0, 0, 0}, {0, 0, 0, 0}};
    uint32_t xvu = 0;
    #pragma unroll
    for (int i = 0; i < 3; ++i)
      ISSUE3(i, b0r + i * 1024 + lane16, b0z + i * 1024 + lane16,
                b0n + i * 1024 + lane16);

    for (int t = 0; t < T_STEPS; ++t) {
      const int p = t & 1, pn = p ^ 1;
      {  // x(t+1) prefetch (plain cached load)
        int t1 = (t + 1 < T_STEPS) ? t + 1 : T_STEPS - 1;
        int r = tid & 31, cc = tid >> 5;
        uint32_t xo = (uint32_t)((((t1 * BATCH) + row0 + r) * IN_DIM +
                                  (cc < 18 ? cc : 17)) * 4);
        asm volatile("global_load_dword %0, %1, %2"
                     : "=&v"(xvu) : "v"(xo), "s"(x) : "memory");
      }
      f32x4 a_r[2] = {{0,0,0,0},{0,0,0,0}}, a_z[2] = {{0,0,0,0},{0,0,0,0}};
      f32x4 a_nx[2] = {{0,0,0,0},{0,0,0,0}}, a_nh[2] = {{0,0,0,0},{0,0,0,0}};
      #pragma unroll
      for (int i = 0; i < KT0; ++i) {
        const int sl = i % 3;
        WAIT3(sl, "6");
        frag_ab A0, A1v;
        if (i == 0) {
          A0  = *(const frag_ab*)&xs[p * 32 + c16][q * 8];
          A1v = *(const frag_ab*)&xs[p * 32 + 16 + c16][q * 8];
        } else {
          A0  = *(const frag_ab*)&h1b[p * 32 + c16][(i - 1) * 32 + q * 8];
          A1v = *(const frag_ab*)&h1b[p * 32 + 16 + c16][(i - 1) * 32 + q * 8];
        }
        a_r[0] = mfma16(A0, rr_[sl], a_r[0]);  a_r[1] = mfma16(A1v, rr_[sl], a_r[1]);
        a_z[0] = mfma16(A0, rz_[sl], a_z[0]);  a_z[1] = mfma16(A1v, rz_[sl], a_z[1]);
        if (i == 0) { a_nx[0] = mfma16(A0, rn_[sl], a_nx[0]);
                      a_nx[1] = mfma16(A1v, rn_[sl], a_nx[1]); }
        else        { a_nh[0] = mfma16(A0, rn_[sl], a_nh[0]);
                      a_nh[1] = mfma16(A1v, rn_[sl], a_nh[1]); }
        const int nk = (i + 3) % KT0;
        ISSUE3(sl, b0r + nk * 1024 + lane16, b0z + nk * 1024 + lane16,
                   b0n + nk * 1024 + lane16);
      }
      // epilogue: x(t+1) stage + h1 update
      { int r = tid & 31, cc = tid >> 5;
        if (cc < 18) xs[pn * 32 + r][cc] = f2bf(__uint_as_float(xvu)); }
      #pragma unroll
      for (int mt = 0; mt < 2; ++mt)
        #pragma unroll
        for (int rrI = 0; rrI < 4; ++rrI) {
          const int row = mt * 16 + q * 4 + rrI;
          float rg = sigmoidf_(a_r[mt][rrI] + brc);
          float zg = sigmoidf_(a_z[mt][rrI] + bzc);
          float ng = tanhf_(a_nx[mt][rrI] + bni + rg * (a_nh[mt][rrI] + bnh));
          float hn = (1.f - zg) * ng + zg * h1m[mt][rrI];
          h1m[mt][rrI] = hn;
          h1b[pn * 32 + row][c] = f2bf(hn);
        }
      BARRIER();
      {  // export frag j = wave (A-operand layout for B)
        const int mt = wave >> 3, kt = wave & 7;
        frag_ab fa = *(const frag_ab*)&h1b[pn * 32 + mt * 16 + c16][kt * 32 + q * 8];
        SCSTORE4(H1SLOT(t, g) + (uint32_t)(wave * 1024 + lane * 16), fa);
      }
      asm volatile("s_waitcnt vmcnt(0)" ::: "memory");
      BARRIER();
      if (tid == 0) { PUBLISH(CNTA(g), t + 1); POLL(CNTB(g), t - 3); }
      BARRIER();
    }

  } else if (bid < 128) {
    // ------------------------ Stage B: xg1 = h1 @ W_ih1^T -----------------
    const int g = bid - 64;
    unsigned short* slab = (unsigned short*)smem;   // [2][16384 B] frag slabs
    const int c = wave * 16 + c16;
    const float bri = bih1[c], bzi = bih1[HID + c], bni = bih1[2 * HID + c];
    if (tid == 0) POLL(CNTA(g), 1);
    BARRIER();
    { uint4v u; SCLOAD4(u, H1SLOT(0, g) + tid * 16);
      asm volatile("s_waitcnt vmcnt(0)" : "+v"(u) :: "memory");
      *(uint4v*)((char*)slab + tid * 16) = u; }
    if (tid == 0) POLL(CNTA(g), 2);
    __syncthreads();

    const uint32_t b1r = (uint32_t)((L0_FRAGS + wave * KT1) << 10);
    const uint32_t b1z = (uint32_t)((L0_FRAGS + (16 + wave) * KT1) << 10);
    const uint32_t b1n = (uint32_t)((L0_FRAGS + (32 + wave) * KT1) << 10);
    frag_ab rr_[4], rz_[4], rn_[4];
    #pragma unroll
    for (int i = 0; i < 4; ++i)
      ISSUE3(i, b1r + i * 1024 + lane16, b1z + i * 1024 + lane16,
                b1n + i * 1024 + lane16);

    for (int t = 0; t < T_STEPS; ++t) {
      const int p = t & 1, pn = p ^ 1;
      uint4v stg = {0, 0, 0, 0};
      const bool hasst = (t + 1 < T_STEPS);
      if (hasst) SCLOAD4(stg, H1SLOT(t + 1, g) + tid * 16);
      f32x4 acc[3][2];
      #pragma unroll
      for (int ga = 0; ga < 3; ++ga) { acc[ga][0] = (f32x4){0,0,0,0};
                                       acc[ga][1] = (f32x4){0,0,0,0}; }
      #pragma unroll
      for (int i = 0; i < 8; ++i) {
        const int sl = i & 3;
        WAIT3(sl, "9");
        frag_ab A0  = *(const frag_ab*)((char*)slab + p * 16384 + (i * 64 + lane) * 16);
        frag_ab A1v = *(const frag_ab*)((char*)slab + p * 16384 + ((8 + i) * 64 + lane) * 16);
        acc[0][0] = mfma16(A0, rr_[sl], acc[0][0]); acc[0][1] = mfma16(A1v, rr_[sl], acc[0][1]);
        acc[1][0] = mfma16(A0, rz_[sl], acc[1][0]); acc[1][1] = mfma16(A1v, rz_[sl], acc[1][1]);
        acc[2][0] = mfma16(A0, rn_[sl], acc[2][0]); acc[2][1] = mfma16(A1v, rn_[sl], acc[2][1]);
        const int nk = (i + 4) & 7;
        ISSUE3(sl, b1r + nk * 1024 + lane16, b1z + nk * 1024 + lane16,
                   b1n + nk * 1024 + lane16);
      }
      if (hasst) *(uint4v*)((char*)slab + pn * 16384 + tid * 16) = stg;
      #pragma unroll
      for (int ga = 0; ga < 3; ++ga) {
        const float bb = (ga == 0) ? bri : (ga == 1) ? bzi : bni;
        const int col = ga * 256 + c;
        #pragma unroll
        for (int mt = 0; mt < 2; ++mt) {
          uint2v u;
          u[0] = (uint32_t)f2bf(acc[ga][mt][0] + bb) |
                 ((uint32_t)f2bf(acc[ga][mt][1] + bb) << 16);
          u[1] = (uint32_t)f2bf(acc[ga][mt][2] + bb) |
                 ((uint32_t)f2bf(acc[ga][mt][3] + bb) << 16);
          SCSTORE2(XGSLOT(t, g) + (uint32_t)((col * 32 + mt * 16 + q * 4) * 2), u);
        }
      }
      asm volatile("s_waitcnt vmcnt(0)" ::: "memory");
      BARRIER();
      if (tid == 0) {
        PUBLISH(CNTB(g), t + 1);
        if (t <= 125) POLL(CNTA(g), t + 3);
        POLL(CNTC(g), t - 3);
      }
      BARRIER();
    }

  } else {
    // ---------------- Stage C: h2 recurrence (W_hh1) + gates + FC ---------
    const int g = bid - 128, row0 = g * 32;
    unsigned short* xg = (unsigned short*)smem;                       // 48 KB
    unsigned short (*h2b)[264] = (unsigned short (*)[264])(smem + 49152);
    for (int i = tid; i < 2 * 32 * 264; i += 1024)
      ((unsigned short*)(smem + 49152))[i] = 0;
    const int c = wave * 16 + c16;
    const float brh = bhh1[c], bzh = bhh1[HID + c], bnh = bhh1[2 * HID + c];
    if (tid == 0) POLL(CNTB(g), 1);
    BARRIER();
    { uint4v u0, u1, u2;
      SCLOAD4(u0, XGSLOT(0, g) + tid * 16);
      SCLOAD4(u1, XGSLOT(0, g) + 16384 + tid * 16);
      SCLOAD4(u2, XGSLOT(0, g) + 32768 + tid * 16);
      asm volatile("s_waitcnt vmcnt(0)" : "+v"(u0), "+v"(u1), "+v"(u2) :: "memory");
      *(uint4v*)((char*)xg + tid * 16) = u0;
      *(uint4v*)((char*)xg + 16384 + tid * 16) = u1;
      *(uint4v*)((char*)xg + 32768 + tid * 16) = u2; }
    if (tid == 0) POLL(CNTB(g), 2);
    __syncthreads();

    const uint32_t bCr = (uint32_t)((L0_FRAGS + wave * KT1 + 8) << 10);
    const uint32_t bCz = (uint32_t)((L0_FRAGS + (16 + wave) * KT1 + 8) << 10);
    const uint32_t bCn = (uint32_t)((L0_FRAGS + (32 + wave) * KT1 + 8) << 10);
    frag_ab rr_[4], rz_[4], rn_[4];
    float h2m[2][4] = {{0, 0, 0, 0}, {0, 0, 0, 0}};
    #pragma unroll
    for (int i = 0; i < 4; ++i)
      ISSUE3(i, bCr + i * 1024 + lane16, bCz + i * 1024 + lane16,
                bCn + i * 1024 + lane16);

    for (int t = 0; t < T_STEPS; ++t) {
      const int p = t & 1, pn = p ^ 1;
      uint4v s0 = {0,0,0,0}, s1 = {0,0,0,0}, s2 = {0,0,0,0};
      const bool hasst = (t + 1 < T_STEPS);
      if (hasst) {
        SCLOAD4(s0, XGSLOT(t + 1, g) + tid * 16);
        SCLOAD4(s1, XGSLOT(t + 1, g) + 16384 + tid * 16);
        SCLOAD4(s2, XGSLOT(t + 1, g) + 32768 + tid * 16);
      }
      f32x4 acc[3][2];
      #pragma unroll
      for (int ga = 0; ga < 3; ++ga) { acc[ga][0] = (f32x4){0,0,0,0};
                                       acc[ga][1] = (f32x4){0,0,0,0}; }
      #pragma unroll
      for (int i = 0; i < 8; ++i) {
        const int sl = i & 3;
        WAIT3(sl, "9");
        frag_ab A0  = *(const frag_ab*)&h2b[p * 32 + c16][i * 32 + q * 8];
        frag_ab A1v = *(const frag_ab*)&h2b[p * 32 + 16 + c16][i * 32 + q * 8];
        acc[0][0] = mfma16(A0, rr_[sl], acc[0][0]); acc[0][1] = mfma16(A1v, rr_[sl], acc[0][1]);
        acc[1][0] = mfma16(A0, rz_[sl], acc[1][0]); acc[1][1] = mfma16(A1v, rz_[sl], acc[1][1]);
        acc[2][0] = mfma16(A0, rn_[sl], acc[2][0]); acc[2][1] = mfma16(A1v, rn_[sl], acc[2][1]);
        const int nk = (i + 4) & 7;
        ISSUE3(sl, bCr + nk * 1024 + lane16, bCz + nk * 1024 + lane16,
                   bCn + nk * 1024 + lane16);
      }
      // epilogue: read xg(t) from LDS, gates, h2 update
      #pragma unroll
      for (int mt = 0; mt < 2; ++mt) {
        uint2v ur = *(const uint2v*)((char*)xg + ((0 * 256 + c) * 32 + mt * 16 + q * 4) * 2);
        uint2v uz = *(const uint2v*)((char*)xg + ((1 * 256 + c) * 32 + mt * 16 + q * 4) * 2);
        uint2v un = *(const uint2v*)((char*)xg + ((2 * 256 + c) * 32 + mt * 16 + q * 4) * 2);
        #pragma unroll
        for (int rrI = 0; rrI < 4; ++rrI) {
          const int row = mt * 16 + q * 4 + rrI;
          const uint32_t wr = (rrI < 2) ? ur[0] : ur[1];
          const uint32_t wz = (rrI < 2) ? uz[0] : uz[1];
          const uint32_t wn = (rrI < 2) ? un[0] : un[1];
          const int sh = (rrI & 1) * 16;
          float xr = bf2f((unsigned short)(wr >> sh));
          float xz = bf2f((unsigned short)(wz >> sh));
          float xn = bf2f((unsigned short)(wn >> sh));
          float rg = sigmoidf_(xr + acc[0][mt][rrI] + brh);
          float zg = sigmoidf_(xz + acc[1][mt][rrI] + bzh);
          float ng = tanhf_(xn + rg * (acc[2][mt][rrI] + bnh));
          float hn = (1.f - zg) * ng + zg * h2m[mt][rrI];
          h2m[mt][rrI] = hn;
          h2b[pn * 32 + row][c] = f2bf(hn);
        }
      }
      BARRIER();   // all xg(t) reads done before overwrite
      if (hasst) {
        *(uint4v*)((char*)xg + tid * 16) = s0;
        *(uint4v*)((char*)xg + 16384 + tid * 16) = s1;
        *(uint4v*)((char*)xg + 32768 + tid * 16) = s2;
      }
      BARRIER();
      if (tid == 0) {
        PUBLISH(CNTC(g), t + 1);
        if (t <= 125) POLL(CNTB(g), t + 3);
      }
      BARRIER();
    }

    // FC head from h2b parity 0 (h2(127): pn of t=127 is 0)
    if (tid < 128) {
      const int row = tid >> 2, o = tid & 3;
      float acc2 = fcb[o];
      #pragma unroll 8
      for (int k = 0; k < HID; ++k)
        acc2 += bf2f(h2b[row][k]) * fcw[o * HID + k];
      float sg = 1.f / (1.f + __expf(-acc2));
      out[(size_t)(row0 + row) * 4 + o] = sg * 2.f - 1.f;
    }
  }
#undef BARRIER
#undef ISSUE3
#undef WAIT3
#undef SCLOAD4
#undef SCSTORE4
#undef SCSTORE2
#undef PUBLISH
#undef POLL
}

extern "C" void kernel_launch(void* const* d_in, const int* in_sizes, int n_in,
                              void* d_out, int out_size, void* d_ws, size_t ws_size,
                              hipStream_t stream) {
  const float* x    = (const float*)d_in[0];
  const float* Wih0 = (const float*)d_in[1];
  const float* Whh0 = (const float*)d_in[2];
  const float* bih0 = (const float*)d_in[3];
  const float* bhh0 = (const float*)d_in[4];
  const float* Wih1 = (const float*)d_in[5];
  const float* Whh1 = (const float*)d_in[6];
  const float* bih1 = (const float*)d_in[7];
  const float* bhh1 = (const float*)d_in[8];
  const float* fcw  = (const float*)d_in[9];
  const float* fcb  = (const float*)d_in[10];

  unsigned short* wq = (unsigned short*)d_ws;
  uint32_t* cnt = (uint32_t*)((char*)d_ws + CNT_OFF);

  repack_w<<<(TOT_FRAGS * 64 + 255) / 256, 256, 0, stream>>>(Wih0, Whh0, Wih1, Whh1, wq);
  clear_cnt<<<12, 256, 0, stream>>>(cnt);
  gru_pipe<<<192, 1024, 0, stream>>>(x, bih0, bhh0, bih1, bhh1, fcw, fcb,
                                     (char*)d_ws, (float*)d_out);
}